// Round 6
// baseline (288.244 us; speedup 1.0000x reference)
//
#include <hip/hip_runtime.h>
#include <math.h>

#define TN 4096
#define HN 2048
#define NB 32
#define NCH 9
#define NCODES 512
#define CDIM 64
#define TAU 1e-3f
#define PTS 128          // points per vq block
#define CHK 64           // codes per LDS chunk
#define NCHK 8

typedef _Float16 f16x8 __attribute__((ext_vector_type(8)));
typedef float f32x4 __attribute__((ext_vector_type(4)));

__device__ __forceinline__ float2 cmulf(float2 a, float2 b) {
    return make_float2(a.x * b.x - a.y * b.y, a.x * b.y + a.y * b.x);
}
__device__ __forceinline__ float2 f2add(float2 a, float2 b) {
    return make_float2(a.x + b.x, a.y + b.y);
}
__device__ __forceinline__ float2 f2sub(float2 a, float2 b) {
    return make_float2(a.x - b.x, a.y - b.y);
}

__device__ __forceinline__ unsigned long long packsi(float s, int i) {
    unsigned u = __float_as_uint(s);
    u = (u & 0x80000000u) ? ~u : (u | 0x80000000u);
    return ((unsigned long long)u << 32) | (unsigned)i;
}
__device__ __forceinline__ float unpacks(unsigned long long v) {
    unsigned u = (unsigned)(v >> 32);
    u = (u & 0x80000000u) ? (u & 0x7fffffffu) : ~u;
    return __uint_as_float(u);
}

__device__ __forceinline__ void gload_lds16(const void* g, void* l) {
    __builtin_amdgcn_global_load_lds(
        (const __attribute__((address_space(1))) unsigned int*)g,
        (__attribute__((address_space(3))) unsigned int*)l, 16, 0, 0);
}

// prep: bid<512 zero phases; bid 512..543: build pre-swizzled f16 hi/lo
// codebook (row = 16 x 16B blocks: [hi d0..63 | lo d0..63], block j holds
// orig block j^(k&15) so linear global_load_lds + swizzled ds_read match);
// bid 544: codebook norms.
__global__ __launch_bounds__(256) void prep_kernel(const float* __restrict__ cb,
                                                   float* __restrict__ cn,
                                                   f16x8* __restrict__ cbswz,
                                                   float* __restrict__ ph) {
    const int bid = blockIdx.x;
    const int tid = threadIdx.x;
    if (bid < 512) {
        ph[bid * 256 + tid] = 0.0f;
        return;
    }
    if (bid < 544) {
        const int u = (bid - 512) * 256 + tid;     // 8192 units total
        const int k = u >> 4;
        const int j = u & 15;
        const int ob = j ^ (k & 15);
        const int plane = ob >> 3;                 // 0 = hi, 1 = lo
        const int d0 = (ob & 7) * 8;
        f16x8 out;
        #pragma unroll
        for (int e = 0; e < 8; ++e) {
            float c = cb[k * CDIM + d0 + e];
            _Float16 hh = (_Float16)c;
            out[e] = plane ? (_Float16)(c - (float)hh) : hh;
        }
        cbswz[u] = out;
        return;
    }
    for (int k = tid; k < NCODES; k += 256) {
        const float4* c4 = (const float4*)(cb + (size_t)k * CDIM);
        float s = 0.0f;
        #pragma unroll
        for (int q = 0; q < 16; ++q) {
            float4 c = c4[q];
            s = fmaf(c.x, c.x, s);
            s = fmaf(c.y, c.y, s);
            s = fmaf(c.z, c.z, s);
            s = fmaf(c.w, c.w, s);
        }
        cn[k] = s;
    }
}

// Paired-row Hilbert (radix-4 Stockham, validated r3/r4). HT=512.
#define HT 512
__global__ __launch_bounds__(HT) void hilbert_phase_kernel(
    const float* __restrict__ x, float* __restrict__ phases) {
    __shared__ float2 bufA[TN];
    __shared__ float2 bufB[TN];
    __shared__ float2 tw[HN];
    const int tid = threadIdx.x;
    const int row1 = 2 * blockIdx.x;
    const int row2 = row1 + 1;
    const int b1 = row1 / NCH;
    const int b2 = row2 / NCH;
    const float* xr1 = x + (size_t)row1 * TN;
    const float* xr2 = x + (size_t)row2 * TN;

    for (int i = tid; i < HN; i += HT) {
        float ang = -3.14159265358979323846f * ((float)i / (float)HN);
        float s, c;
        sincosf(ang, &s, &c);
        tw[i] = make_float2(c, s);
    }
    for (int i = tid; i < TN; i += HT) {
        bufA[i] = make_float2(xr1[i], xr2[i]);
    }
    __syncthreads();

    float2* src = bufA;
    float2* dst = bufB;
    for (int stage = 0; stage < 6; ++stage) {
        const int m = 1 << (2 * stage);
        for (int idx = tid; idx < 1024; idx += HT) {
            const int kk = idx & (m - 1);
            const int jm = idx - kk;
            float2 a0 = src[idx];
            float2 a1 = src[idx + 1024];
            float2 a2 = src[idx + 2048];
            float2 a3 = src[idx + 3072];
            float2 b0 = f2add(a0, a2);
            float2 b1 = f2add(a1, a3);
            float2 b2 = f2sub(a0, a2);
            float2 b3 = f2sub(a1, a3);
            float2 w1 = tw[jm];
            float2 w2 = tw[2 * jm];
            float2 w3 = cmulf(w1, w2);
            float2 y0 = f2add(b0, b1);
            float2 mi = make_float2(b2.x + b3.y, b2.y - b3.x);
            float2 pi_ = make_float2(b2.x - b3.y, b2.y + b3.x);
            dst[4 * jm + kk]         = y0;
            dst[4 * jm + kk + m]     = cmulf(mi, w1);
            dst[4 * jm + kk + 2 * m] = cmulf(f2sub(b0, b1), w2);
            dst[4 * jm + kk + 3 * m] = cmulf(pi_, w3);
        }
        __syncthreads();
        float2* t0 = src; src = dst; dst = t0;
    }
    const float inv = 1.0f / (float)TN;
    for (int i = tid; i < TN; i += HT) {
        float sc;
        if (i == 0 || i == HN) sc = inv;
        else if (i < HN) sc = 2.0f * inv;
        else sc = 0.0f;
        float2 v = src[i];
        v.x *= sc; v.y *= sc;
        src[i] = v;
    }
    __syncthreads();
    for (int stage = 0; stage < 6; ++stage) {
        const int m = 1 << (2 * stage);
        for (int idx = tid; idx < 1024; idx += HT) {
            const int kk = idx & (m - 1);
            const int jm = idx - kk;
            float2 a0 = src[idx];
            float2 a1 = src[idx + 1024];
            float2 a2 = src[idx + 2048];
            float2 a3 = src[idx + 3072];
            float2 b0 = f2add(a0, a2);
            float2 b1 = f2add(a1, a3);
            float2 b2 = f2sub(a0, a2);
            float2 b3 = f2sub(a1, a3);
            float2 w1 = tw[jm];      w1.y = -w1.y;
            float2 w2 = tw[2 * jm];  w2.y = -w2.y;
            float2 w3 = cmulf(w1, w2);
            float2 y0 = f2add(b0, b1);
            float2 pi_ = make_float2(b2.x - b3.y, b2.y + b3.x);
            float2 mi = make_float2(b2.x + b3.y, b2.y - b3.x);
            dst[4 * jm + kk]         = y0;
            dst[4 * jm + kk + m]     = cmulf(pi_, w1);
            dst[4 * jm + kk + 2 * m] = cmulf(f2sub(b0, b1), w2);
            dst[4 * jm + kk + 3 * m] = cmulf(mi, w3);
        }
        __syncthreads();
        float2* t0 = src; src = dst; dst = t0;
    }
    float* ph1 = phases + (size_t)b1 * TN;
    float* ph2 = phases + (size_t)b2 * TN;
    for (int i = tid; i < TN; i += HT) {
        float2 d = src[i];
        float x1v = xr1[i];
        float x2v = xr2[i];
        atomicAdd(&ph1[i], atan2f(d.y - x2v, x1v) * (1.0f / 9.0f));
        atomicAdd(&ph2[i], atan2f(x1v - d.x, x2v) * (1.0f / 9.0f));
    }
}

// vq: 1024 blocks x 256 thr (4 waves). 128 points/block; wave owns 32 points
// (2 row-frags), scans all 512 codes in 8 LDS chunks (global_load_lds staged,
// double-buffered, XOR-swizzled ds_read_b128). f16 hi/lo MFMA; top-2 + rare
// exact f32 rescan (recomputes features).
__global__ __launch_bounds__(256, 2) void vq_kernel(
    const float* __restrict__ imu,
    const float* __restrict__ Wm, const float* __restrict__ bm,
    const float* __restrict__ Wp, const float* __restrict__ bp,
    const float* __restrict__ cb,
    const float* __restrict__ cn,
    const f16x8* __restrict__ cbswz,
    const float* __restrict__ phases,
    float* __restrict__ out_q, float* __restrict__ out_i) {
    __shared__ __align__(16) _Float16 sA[PTS][128];      // 32 KB
    __shared__ __align__(16) _Float16 sB[2][CHK][128];   // 2 x 16 KB
    __shared__ int s_idx[PTS];
    const int tid = threadIdx.x;
    const int lane = tid & 63;
    const int w = tid >> 6;
    const int l15 = lane & 15;
    const int hi16 = lane >> 4;
    const int p0 = blockIdx.x * PTS;

    // ---- features: thread = (point pl, half h); h wave-uniform ----
    {
        const int pl = tid & 127;
        const int h = tid >> 7;
        const int p = p0 + pl;
        const int bb = p >> 12;
        const int tt = p & (TN - 1);
        float xc[9];
        #pragma unroll
        for (int c = 0; c < 9; ++c)
            xc[c] = imu[((size_t)(bb * 9 + c)) * TN + tt];
        float v[32];
        if (h == 0) {
            #pragma unroll
            for (int j = 0; j < 32; ++j) {
                float a = bm[j];
                #pragma unroll
                for (int c = 0; c < 9; ++c) a = fmaf(Wm[j * 9 + c], xc[c], a);
                v[j] = a;
            }
        } else {
            float sp, cp;
            sincosf(phases[p], &sp, &cp);
            #pragma unroll
            for (int j = 0; j < 32; ++j) {
                float a = bp[j];
                #pragma unroll
                for (int c = 0; c < 7; ++c) a = fmaf(Wp[j * 9 + c], xc[c], a);
                a = fmaf(Wp[j * 9 + 7], cp, a);
                a = fmaf(Wp[j * 9 + 8], sp, a);
                v[j] = a;
            }
        }
        f16x8* rowp = (f16x8*)&sA[pl][0];
        #pragma unroll
        for (int q = 0; q < 4; ++q) {
            f16x8 hv, lv;
            #pragma unroll
            for (int e = 0; e < 8; ++e) {
                float val = v[8 * q + e];
                _Float16 hh = (_Float16)val;
                hv[e] = hh;
                lv[e] = (_Float16)(val - (float)hh);
            }
            rowp[(4 * h + q) ^ (pl & 15)] = hv;
            rowp[(8 + 4 * h + q) ^ (pl & 15)] = lv;
        }
    }

    // stage chunk 0 into buffer 0
    {
        const char* gsrc = (const char*)cbswz;
        char* ldst = (char*)&sB[0][0][0];
        #pragma unroll
        for (int i = 0; i < 4; ++i) {
            const int u = i * 256 + tid;
            gload_lds16(gsrc + (size_t)u * 16, ldst + u * 16);
        }
    }
    __syncthreads();   // barrier drains ds_writes (sA) + global_load_lds (sB0)

    // ---- A fragments: wave w rows [32w, 32w+32) ----
    f16x8 aH[2][2], aL[2][2];    // [rowfrag][kchunk]
    #pragma unroll
    for (int rf = 0; rf < 2; ++rf) {
        const int row = 32 * w + 16 * rf + l15;
        const f16x8* rowp = (const f16x8*)&sA[row][0];
        #pragma unroll
        for (int s = 0; s < 2; ++s) {
            aH[rf][s] = rowp[(4 * s + hi16) ^ (row & 15)];
            aL[rf][s] = rowp[(8 + 4 * s + hi16) ^ (row & 15)];
        }
    }

    float best[2][4], sec[2][4];
    int bidx[2][4];
    #pragma unroll
    for (int rf = 0; rf < 2; ++rf)
        #pragma unroll
        for (int r = 0; r < 4; ++r) {
            best[rf][r] = 3.4e38f; sec[rf][r] = 3.4e38f; bidx[rf][r] = 0;
        }

    for (int ch = 0; ch < NCHK; ++ch) {
        const int cur = ch & 1;
        if (ch < NCHK - 1) {     // stage next chunk while computing this one
            const char* gsrc = (const char*)cbswz + (size_t)(ch + 1) * CHK * 256;
            char* ldst = (char*)&sB[cur ^ 1][0][0];
            #pragma unroll
            for (int i = 0; i < 4; ++i) {
                const int u = i * 256 + tid;
                gload_lds16(gsrc + (size_t)u * 16, ldst + u * 16);
            }
        }
        float cnv[4];
        #pragma unroll
        for (int cf = 0; cf < 4; ++cf) cnv[cf] = cn[ch * CHK + 16 * cf + l15];

        f32x4 acc[2][4];
        #pragma unroll
        for (int rf = 0; rf < 2; ++rf)
            #pragma unroll
            for (int cf = 0; cf < 4; ++cf) acc[rf][cf] = (f32x4){0.f, 0.f, 0.f, 0.f};

        #pragma unroll
        for (int cf = 0; cf < 4; ++cf) {
            const int cl = 16 * cf + l15;
            const f16x8* brow = (const f16x8*)&sB[cur][cl][0];
            #pragma unroll
            for (int s = 0; s < 2; ++s) {
                f16x8 bH = brow[(4 * s + hi16) ^ l15];
                f16x8 bL = brow[(8 + 4 * s + hi16) ^ l15];
                #pragma unroll
                for (int rf = 0; rf < 2; ++rf) {
                    acc[rf][cf] = __builtin_amdgcn_mfma_f32_16x16x32_f16(aH[rf][s], bH, acc[rf][cf], 0, 0, 0);
                    acc[rf][cf] = __builtin_amdgcn_mfma_f32_16x16x32_f16(aH[rf][s], bL, acc[rf][cf], 0, 0, 0);
                    acc[rf][cf] = __builtin_amdgcn_mfma_f32_16x16x32_f16(aL[rf][s], bH, acc[rf][cf], 0, 0, 0);
                }
            }
        }
        #pragma unroll
        for (int cf = 0; cf < 4; ++cf) {
            const int col = ch * CHK + 16 * cf + l15;
            #pragma unroll
            for (int rf = 0; rf < 2; ++rf)
                #pragma unroll
                for (int r = 0; r < 4; ++r) {
                    float sc = fmaf(-2.0f, acc[rf][cf][r], cnv[cf]);
                    bool lt = sc < best[rf][r];
                    float cand = lt ? best[rf][r] : sc;
                    sec[rf][r] = fminf(sec[rf][r], cand);
                    best[rf][r] = fminf(best[rf][r], sc);
                    bidx[rf][r] = lt ? col : bidx[rf][r];
                }
        }
        __syncthreads();   // drains next-chunk staging; all waves done with cur
    }

    // ---- cross-lane top-2 merge within 16-lane groups ----
    unsigned long long pb[2][4], ps[2][4];
    #pragma unroll
    for (int rf = 0; rf < 2; ++rf)
        #pragma unroll
        for (int r = 0; r < 4; ++r) {
            pb[rf][r] = packsi(best[rf][r], bidx[rf][r]);
            ps[rf][r] = packsi(sec[rf][r], 0);
        }
    #pragma unroll
    for (int m = 1; m <= 8; m <<= 1) {
        #pragma unroll
        for (int rf = 0; rf < 2; ++rf)
            #pragma unroll
            for (int r = 0; r < 4; ++r) {
                unsigned long long ob = __shfl_xor(pb[rf][r], m, 64);
                unsigned long long os = __shfl_xor(ps[rf][r], m, 64);
                unsigned long long mx = pb[rf][r] > ob ? pb[rf][r] : ob;
                unsigned long long mn = ps[rf][r] < os ? ps[rf][r] : os;
                ps[rf][r] = mx < mn ? mx : mn;
                pb[rf][r] = pb[rf][r] < ob ? pb[rf][r] : ob;
            }
    }
    if (l15 == 0) {
        #pragma unroll
        for (int rf = 0; rf < 2; ++rf)
            #pragma unroll
            for (int r = 0; r < 4; ++r) {
                const int row = 32 * w + 16 * rf + 4 * hi16 + r;
                const int bi = (int)(pb[rf][r] & 0xFFFFFFFFu);
                s_idx[row] = bi;
                out_i[p0 + row] = (float)bi;
            }
    }

    // ---- rare exact f32 rescan of near-tie rows (ballot-driven) ----
    #pragma unroll
    for (int rf = 0; rf < 2; ++rf)
        #pragma unroll
        for (int r = 0; r < 4; ++r) {
            float gap = unpacks(ps[rf][r]) - unpacks(pb[rf][r]);
            unsigned long long bal = __ballot(l15 == 0 && gap < TAU);
            while (bal) {
                const int ln = __builtin_ctzll(bal);
                bal &= bal - 1;
                const int row = 32 * w + 16 * rf + (ln >> 4) * 4 + r;
                const int p = p0 + row;
                const int bb2 = p >> 12;
                const int tt2 = p & (TN - 1);
                float xc2[9];
                #pragma unroll
                for (int c = 0; c < 9; ++c)
                    xc2[c] = imu[((size_t)(bb2 * 9 + c)) * TN + tt2];
                float sp2, cp2;
                sincosf(phases[p], &sp2, &cp2);
                float fr[CDIM];
                #pragma unroll
                for (int j = 0; j < 32; ++j) {
                    float a = bm[j];
                    #pragma unroll
                    for (int c = 0; c < 9; ++c) a = fmaf(Wm[j * 9 + c], xc2[c], a);
                    fr[j] = a;
                }
                #pragma unroll
                for (int j = 0; j < 32; ++j) {
                    float a = bp[j];
                    #pragma unroll
                    for (int c = 0; c < 7; ++c) a = fmaf(Wp[j * 9 + c], xc2[c], a);
                    a = fmaf(Wp[j * 9 + 7], cp2, a);
                    a = fmaf(Wp[j * 9 + 8], sp2, a);
                    fr[32 + j] = a;
                }
                unsigned long long pbest = ~0ull;
                #pragma unroll
                for (int cc = 0; cc < 8; ++cc) {
                    const int kk = lane * 8 + cc;
                    const float4* crow = (const float4*)(cb + (size_t)kk * CDIM);
                    float a0 = 0.f, a1 = 0.f, a2 = 0.f, a3 = 0.f;
                    #pragma unroll
                    for (int d4 = 0; d4 < 16; ++d4) {
                        float4 cv = crow[d4];
                        a0 = fmaf(fr[4 * d4 + 0], cv.x, a0);
                        a1 = fmaf(fr[4 * d4 + 1], cv.y, a1);
                        a2 = fmaf(fr[4 * d4 + 2], cv.z, a2);
                        a3 = fmaf(fr[4 * d4 + 3], cv.w, a3);
                    }
                    float sc = fmaf(-2.0f, (a0 + a1) + (a2 + a3), cn[kk]);
                    unsigned long long pk = packsi(sc, kk);
                    pbest = pk < pbest ? pk : pbest;
                }
                #pragma unroll
                for (int m = 1; m <= 32; m <<= 1) {
                    unsigned long long o = __shfl_xor(pbest, m, 64);
                    pbest = o < pbest ? o : pbest;
                }
                if (lane == 0) {
                    const int bi = (int)(pbest & 0xFFFFFFFFu);
                    s_idx[row] = bi;
                    out_i[p0 + row] = (float)bi;
                }
            }
        }
    __syncthreads();

    // ---- cooperative coalesced gather of quantized rows (L2-hot cb) ----
    float4* oq = (float4*)out_q;
    const float4* c4g = (const float4*)cb;
    for (int i = tid; i < PTS * 16; i += 256) {
        const int pt = i >> 4;
        const int q = i & 15;
        oq[(size_t)(p0 + pt) * 16 + q] = c4g[(size_t)s_idx[pt] * 16 + q];
    }
}

extern "C" void kernel_launch(void* const* d_in, const int* in_sizes, int n_in,
                              void* d_out, int out_size, void* d_ws, size_t ws_size,
                              hipStream_t stream) {
    const float* imu = (const float*)d_in[0];
    const float* Wm  = (const float*)d_in[1];
    const float* bm  = (const float*)d_in[2];
    const float* Wp  = (const float*)d_in[3];
    const float* bp  = (const float*)d_in[4];
    const float* cb  = (const float*)d_in[5];

    float* out_q = (float*)d_out;                          // (32,4096,64)
    float* out_i = out_q + (size_t)NB * TN * CDIM;         // (32,4096) as float
    float* out_p = out_i + (size_t)NB * TN;                // (32,4096) phases

    float* cn     = (float*)d_ws;                          // 512 f32
    f16x8* cbswz  = (f16x8*)((char*)d_ws + 2048);          // 128 KB pre-swizzled

    prep_kernel<<<545, 256, 0, stream>>>(cb, cn, cbswz, out_p);
    hilbert_phase_kernel<<<NB * NCH / 2, HT, 0, stream>>>(imu, out_p);
    vq_kernel<<<(NB * TN) / PTS, 256, 0, stream>>>(imu, Wm, bm, Wp, bp, cb,
                                                   cn, cbswz, out_p, out_q, out_i);
}

// Round 7
// 160.087 us; speedup vs baseline: 1.8005x; 1.8005x over previous
//
#include <hip/hip_runtime.h>
#include <math.h>

#define TN 4096
#define HN 2048
#define NB 32
#define NCH 9
#define NCODES 512
#define CDIM 64
#define TAU 1e-3f
#define PTS 128          // points per vq block
#define CHK 64           // codes per LDS chunk
#define NCHK 8

typedef _Float16 f16x8 __attribute__((ext_vector_type(8)));
typedef float f32x4 __attribute__((ext_vector_type(4)));

__device__ __forceinline__ float2 cmulf(float2 a, float2 b) {
    return make_float2(a.x * b.x - a.y * b.y, a.x * b.y + a.y * b.x);
}
__device__ __forceinline__ float2 f2add(float2 a, float2 b) {
    return make_float2(a.x + b.x, a.y + b.y);
}
__device__ __forceinline__ float2 f2sub(float2 a, float2 b) {
    return make_float2(a.x - b.x, a.y - b.y);
}

__device__ __forceinline__ unsigned long long packsi(float s, int i) {
    unsigned u = __float_as_uint(s);
    u = (u & 0x80000000u) ? ~u : (u | 0x80000000u);
    return ((unsigned long long)u << 32) | (unsigned)i;
}
__device__ __forceinline__ float unpacks(unsigned long long v) {
    unsigned u = (unsigned)(v >> 32);
    u = (u & 0x80000000u) ? (u & 0x7fffffffu) : ~u;
    return __uint_as_float(u);
}

__device__ __forceinline__ void gload_lds16(const void* g, void* l) {
    __builtin_amdgcn_global_load_lds(
        (const __attribute__((address_space(1))) unsigned int*)g,
        (__attribute__((address_space(3))) unsigned int*)l, 16, 0, 0);
}

// A-tile unit index: [p>>4][plane][s][hi16][l15] of 16B f16x8 units.
__device__ __forceinline__ size_t aunit(int pbase, int plane, int s, int hi16, int l15) {
    return ((size_t)(((pbase * 2 + plane) * 2 + s) * 4 + hi16) << 4) + l15;
}

// prep: bid<512 zero phases; bid 512..543: pre-swizzled f16 hi/lo codebook
// (unit j of code k holds orig 16B block j^(k&15)); bid 544: codebook norms.
__global__ __launch_bounds__(256) void prep_kernel(const float* __restrict__ cb,
                                                   float* __restrict__ cn,
                                                   f16x8* __restrict__ cbswz,
                                                   float* __restrict__ ph) {
    const int bid = blockIdx.x;
    const int tid = threadIdx.x;
    if (bid < 512) {
        ph[bid * 256 + tid] = 0.0f;
        return;
    }
    if (bid < 544) {
        const int u = (bid - 512) * 256 + tid;
        const int k = u >> 4;
        const int j = u & 15;
        const int ob = j ^ (k & 15);
        const int plane = ob >> 3;
        const int d0 = (ob & 7) * 8;
        f16x8 out;
        #pragma unroll
        for (int e = 0; e < 8; ++e) {
            float c = cb[k * CDIM + d0 + e];
            _Float16 hh = (_Float16)c;
            out[e] = plane ? (_Float16)(c - (float)hh) : hh;
        }
        cbswz[u] = out;
        return;
    }
    for (int k = tid; k < NCODES; k += 256) {
        const float4* c4 = (const float4*)(cb + (size_t)k * CDIM);
        float s = 0.0f;
        #pragma unroll
        for (int q = 0; q < 16; ++q) {
            float4 c = c4[q];
            s = fmaf(c.x, c.x, s);
            s = fmaf(c.y, c.y, s);
            s = fmaf(c.z, c.z, s);
            s = fmaf(c.w, c.w, s);
        }
        cn[k] = s;
    }
}

// Paired-row Hilbert (radix-4 Stockham, validated r3-r6). HT=512.
#define HT 512
__global__ __launch_bounds__(HT) void hilbert_phase_kernel(
    const float* __restrict__ x, float* __restrict__ phases) {
    __shared__ float2 bufA[TN];
    __shared__ float2 bufB[TN];
    __shared__ float2 tw[HN];
    const int tid = threadIdx.x;
    const int row1 = 2 * blockIdx.x;
    const int row2 = row1 + 1;
    const int b1 = row1 / NCH;
    const int b2 = row2 / NCH;
    const float* xr1 = x + (size_t)row1 * TN;
    const float* xr2 = x + (size_t)row2 * TN;

    for (int i = tid; i < HN; i += HT) {
        float ang = -3.14159265358979323846f * ((float)i / (float)HN);
        float s, c;
        sincosf(ang, &s, &c);
        tw[i] = make_float2(c, s);
    }
    for (int i = tid; i < TN; i += HT) {
        bufA[i] = make_float2(xr1[i], xr2[i]);
    }
    __syncthreads();

    float2* src = bufA;
    float2* dst = bufB;
    for (int stage = 0; stage < 6; ++stage) {
        const int m = 1 << (2 * stage);
        for (int idx = tid; idx < 1024; idx += HT) {
            const int kk = idx & (m - 1);
            const int jm = idx - kk;
            float2 a0 = src[idx];
            float2 a1 = src[idx + 1024];
            float2 a2 = src[idx + 2048];
            float2 a3 = src[idx + 3072];
            float2 b0 = f2add(a0, a2);
            float2 b1 = f2add(a1, a3);
            float2 b2 = f2sub(a0, a2);
            float2 b3 = f2sub(a1, a3);
            float2 w1 = tw[jm];
            float2 w2 = tw[2 * jm];
            float2 w3 = cmulf(w1, w2);
            float2 y0 = f2add(b0, b1);
            float2 mi = make_float2(b2.x + b3.y, b2.y - b3.x);
            float2 pi_ = make_float2(b2.x - b3.y, b2.y + b3.x);
            dst[4 * jm + kk]         = y0;
            dst[4 * jm + kk + m]     = cmulf(mi, w1);
            dst[4 * jm + kk + 2 * m] = cmulf(f2sub(b0, b1), w2);
            dst[4 * jm + kk + 3 * m] = cmulf(pi_, w3);
        }
        __syncthreads();
        float2* t0 = src; src = dst; dst = t0;
    }
    const float inv = 1.0f / (float)TN;
    for (int i = tid; i < TN; i += HT) {
        float sc;
        if (i == 0 || i == HN) sc = inv;
        else if (i < HN) sc = 2.0f * inv;
        else sc = 0.0f;
        float2 v = src[i];
        v.x *= sc; v.y *= sc;
        src[i] = v;
    }
    __syncthreads();
    for (int stage = 0; stage < 6; ++stage) {
        const int m = 1 << (2 * stage);
        for (int idx = tid; idx < 1024; idx += HT) {
            const int kk = idx & (m - 1);
            const int jm = idx - kk;
            float2 a0 = src[idx];
            float2 a1 = src[idx + 1024];
            float2 a2 = src[idx + 2048];
            float2 a3 = src[idx + 3072];
            float2 b0 = f2add(a0, a2);
            float2 b1 = f2add(a1, a3);
            float2 b2 = f2sub(a0, a2);
            float2 b3 = f2sub(a1, a3);
            float2 w1 = tw[jm];      w1.y = -w1.y;
            float2 w2 = tw[2 * jm];  w2.y = -w2.y;
            float2 w3 = cmulf(w1, w2);
            float2 y0 = f2add(b0, b1);
            float2 pi_ = make_float2(b2.x - b3.y, b2.y + b3.x);
            float2 mi = make_float2(b2.x + b3.y, b2.y - b3.x);
            dst[4 * jm + kk]         = y0;
            dst[4 * jm + kk + m]     = cmulf(pi_, w1);
            dst[4 * jm + kk + 2 * m] = cmulf(f2sub(b0, b1), w2);
            dst[4 * jm + kk + 3 * m] = cmulf(mi, w3);
        }
        __syncthreads();
        float2* t0 = src; src = dst; dst = t0;
    }
    float* ph1 = phases + (size_t)b1 * TN;
    float* ph2 = phases + (size_t)b2 * TN;
    for (int i = tid; i < TN; i += HT) {
        float2 d = src[i];
        float x1v = xr1[i];
        float x2v = xr2[i];
        atomicAdd(&ph1[i], atan2f(d.y - x2v, x1v) * (1.0f / 9.0f));
        atomicAdd(&ph2[i], atan2f(x1v - d.x, x2v) * (1.0f / 9.0f));
    }
}

// feat: 512 blocks x 256 thr, 1 point/thread. Computes features in 8-dim
// groups (v8[8]+xc[9] live only -> no spill), writes f16 hi/lo A-fragment
// tiles in MFMA order into the out_q region (vq reads them before its
// final gather overwrites the same bytes; each vq block's tiles live in
// its own out_q slice).
__global__ __launch_bounds__(256) void feat_kernel(
    const float* __restrict__ imu,
    const float* __restrict__ Wm, const float* __restrict__ bm,
    const float* __restrict__ Wp, const float* __restrict__ bp,
    const float* __restrict__ phases,
    f16x8* __restrict__ atiles) {
    const int p = blockIdx.x * 256 + threadIdx.x;
    const int bb = p >> 12;
    const int tt = p & (TN - 1);
    float xc[9];
    #pragma unroll
    for (int c = 0; c < 9; ++c)
        xc[c] = imu[((size_t)(bb * 9 + c)) * TN + tt];
    float sp, cp;
    sincosf(phases[p], &sp, &cp);

    const int pbase = p >> 4;
    const int l15 = p & 15;
    #pragma unroll
    for (int g = 0; g < 8; ++g) {
        float v8[8];
        if (g < 4) {
            #pragma unroll
            for (int e = 0; e < 8; ++e) {
                const int j = 8 * g + e;
                float a = bm[j];
                #pragma unroll
                for (int c = 0; c < 9; ++c) a = fmaf(Wm[j * 9 + c], xc[c], a);
                v8[e] = a;
            }
        } else {
            #pragma unroll
            for (int e = 0; e < 8; ++e) {
                const int j = 8 * (g - 4) + e;
                float a = bp[j];
                #pragma unroll
                for (int c = 0; c < 7; ++c) a = fmaf(Wp[j * 9 + c], xc[c], a);
                a = fmaf(Wp[j * 9 + 7], cp, a);
                a = fmaf(Wp[j * 9 + 8], sp, a);
                v8[e] = a;
            }
        }
        f16x8 hv, lv;
        #pragma unroll
        for (int e = 0; e < 8; ++e) {
            _Float16 hh = (_Float16)v8[e];
            hv[e] = hh;
            lv[e] = (_Float16)(v8[e] - (float)hh);
        }
        const int s = g >> 2;
        const int hi16 = g & 3;
        atiles[aunit(pbase, 0, s, hi16, l15)] = hv;
        atiles[aunit(pbase, 1, s, hi16, l15)] = lv;
    }
}

// vq: 1024 blocks x 256 thr (4 waves). A-frags from global tiles (regs),
// B staged chunk-wise in LDS (global_load_lds, dbuf, pre-swizzled reads).
// Tiny register state -> no spill. Top-2 + rare exact f32 streaming rescan.
__global__ __launch_bounds__(256, 2) void vq_kernel(
    const float* __restrict__ imu,
    const float* __restrict__ Wm, const float* __restrict__ bm,
    const float* __restrict__ Wp, const float* __restrict__ bp,
    const float* __restrict__ cb,
    const float* __restrict__ cn,
    const f16x8* __restrict__ cbswz,
    const float* __restrict__ phases,
    const f16x8* atiles,           // aliases out_q (no __restrict__)
    float* out_q,
    float* __restrict__ out_i) {
    __shared__ __align__(16) _Float16 sB[2][CHK][128];   // 2 x 16 KB
    __shared__ int s_idx[PTS];
    const int tid = threadIdx.x;
    const int lane = tid & 63;
    const int w = tid >> 6;
    const int l15 = lane & 15;
    const int hi16 = lane >> 4;
    const int p0 = blockIdx.x * PTS;

    // stage chunk 0 into buffer 0
    {
        const char* gsrc = (const char*)cbswz;
        char* ldst = (char*)&sB[0][0][0];
        #pragma unroll
        for (int i = 0; i < 4; ++i) {
            const int u = i * 256 + tid;
            gload_lds16(gsrc + (size_t)u * 16, ldst + u * 16);
        }
    }

    // ---- A fragments from global tiles (held in regs all kernel) ----
    f16x8 aH[2][2], aL[2][2];
    #pragma unroll
    for (int rf = 0; rf < 2; ++rf) {
        const int prow = p0 + 32 * w + 16 * rf + l15;
        const int pbase = prow >> 4;
        #pragma unroll
        for (int s = 0; s < 2; ++s) {
            aH[rf][s] = atiles[aunit(pbase, 0, s, hi16, l15)];
            aL[rf][s] = atiles[aunit(pbase, 1, s, hi16, l15)];
        }
    }
    __syncthreads();   // drains A loads + chunk-0 staging

    float best[2][4], sec[2][4];
    int bidx[2][4];
    #pragma unroll
    for (int rf = 0; rf < 2; ++rf)
        #pragma unroll
        for (int r = 0; r < 4; ++r) {
            best[rf][r] = 3.4e38f; sec[rf][r] = 3.4e38f; bidx[rf][r] = 0;
        }

    for (int ch = 0; ch < NCHK; ++ch) {
        const int cur = ch & 1;
        if (ch < NCHK - 1) {
            const char* gsrc = (const char*)cbswz + (size_t)(ch + 1) * CHK * 256;
            char* ldst = (char*)&sB[cur ^ 1][0][0];
            #pragma unroll
            for (int i = 0; i < 4; ++i) {
                const int u = i * 256 + tid;
                gload_lds16(gsrc + (size_t)u * 16, ldst + u * 16);
            }
        }
        float cnv[4];
        #pragma unroll
        for (int cf = 0; cf < 4; ++cf) cnv[cf] = cn[ch * CHK + 16 * cf + l15];

        f32x4 acc[2][4];
        #pragma unroll
        for (int rf = 0; rf < 2; ++rf)
            #pragma unroll
            for (int cf = 0; cf < 4; ++cf) acc[rf][cf] = (f32x4){0.f, 0.f, 0.f, 0.f};

        #pragma unroll
        for (int cf = 0; cf < 4; ++cf) {
            const int cl = 16 * cf + l15;
            const f16x8* brow = (const f16x8*)&sB[cur][cl][0];
            #pragma unroll
            for (int s = 0; s < 2; ++s) {
                f16x8 bH = brow[(4 * s + hi16) ^ l15];
                f16x8 bL = brow[(8 + 4 * s + hi16) ^ l15];
                #pragma unroll
                for (int rf = 0; rf < 2; ++rf) {
                    acc[rf][cf] = __builtin_amdgcn_mfma_f32_16x16x32_f16(aH[rf][s], bH, acc[rf][cf], 0, 0, 0);
                    acc[rf][cf] = __builtin_amdgcn_mfma_f32_16x16x32_f16(aH[rf][s], bL, acc[rf][cf], 0, 0, 0);
                    acc[rf][cf] = __builtin_amdgcn_mfma_f32_16x16x32_f16(aL[rf][s], bH, acc[rf][cf], 0, 0, 0);
                }
            }
        }
        #pragma unroll
        for (int cf = 0; cf < 4; ++cf) {
            const int col = ch * CHK + 16 * cf + l15;
            #pragma unroll
            for (int rf = 0; rf < 2; ++rf)
                #pragma unroll
                for (int r = 0; r < 4; ++r) {
                    float sc = fmaf(-2.0f, acc[rf][cf][r], cnv[cf]);
                    bool lt = sc < best[rf][r];
                    float cand = lt ? best[rf][r] : sc;
                    sec[rf][r] = fminf(sec[rf][r], cand);
                    best[rf][r] = fminf(best[rf][r], sc);
                    bidx[rf][r] = lt ? col : bidx[rf][r];
                }
        }
        __syncthreads();
    }

    // ---- cross-lane top-2 merge within 16-lane groups ----
    unsigned long long pb[2][4], ps[2][4];
    #pragma unroll
    for (int rf = 0; rf < 2; ++rf)
        #pragma unroll
        for (int r = 0; r < 4; ++r) {
            pb[rf][r] = packsi(best[rf][r], bidx[rf][r]);
            ps[rf][r] = packsi(sec[rf][r], 0);
        }
    #pragma unroll
    for (int m = 1; m <= 8; m <<= 1) {
        #pragma unroll
        for (int rf = 0; rf < 2; ++rf)
            #pragma unroll
            for (int r = 0; r < 4; ++r) {
                unsigned long long ob = __shfl_xor(pb[rf][r], m, 64);
                unsigned long long os = __shfl_xor(ps[rf][r], m, 64);
                unsigned long long mx = pb[rf][r] > ob ? pb[rf][r] : ob;
                unsigned long long mn = ps[rf][r] < os ? ps[rf][r] : os;
                ps[rf][r] = mx < mn ? mx : mn;
                pb[rf][r] = pb[rf][r] < ob ? pb[rf][r] : ob;
            }
    }
    if (l15 == 0) {
        #pragma unroll
        for (int rf = 0; rf < 2; ++rf)
            #pragma unroll
            for (int r = 0; r < 4; ++r) {
                const int row = 32 * w + 16 * rf + 4 * hi16 + r;
                const int bi = (int)(pb[rf][r] & 0xFFFFFFFFu);
                s_idx[row] = bi;
                out_i[p0 + row] = (float)bi;
            }
    }

    // ---- rare exact f32 rescan (streaming feature recompute; no arrays) ----
    #pragma unroll
    for (int rf = 0; rf < 2; ++rf)
        #pragma unroll
        for (int r = 0; r < 4; ++r) {
            float gap = unpacks(ps[rf][r]) - unpacks(pb[rf][r]);
            unsigned long long bal = __ballot(l15 == 0 && gap < TAU);
            while (bal) {
                const int ln = __builtin_ctzll(bal);
                bal &= bal - 1;
                const int row = 32 * w + 16 * rf + (ln >> 4) * 4 + r;
                const int pR = p0 + row;
                const int bbR = pR >> 12;
                const int ttR = pR & (TN - 1);
                float xcR[9];
                #pragma unroll
                for (int c = 0; c < 9; ++c)
                    xcR[c] = imu[((size_t)(bbR * 9 + c)) * TN + ttR];
                float spR, cpR;
                sincosf(phases[pR], &spR, &cpR);
                float a0[8], a1[8], a2[8], a3[8];
                #pragma unroll
                for (int cc = 0; cc < 8; ++cc) {
                    a0[cc] = 0.f; a1[cc] = 0.f; a2[cc] = 0.f; a3[cc] = 0.f;
                }
                for (int d4 = 0; d4 < 16; ++d4) {
                    float fd[4];
                    #pragma unroll
                    for (int e = 0; e < 4; ++e) {
                        const int j = 4 * d4 + e;
                        float a;
                        if (j < 32) {
                            a = bm[j];
                            #pragma unroll
                            for (int c = 0; c < 9; ++c) a = fmaf(Wm[j * 9 + c], xcR[c], a);
                        } else {
                            const int jj = j - 32;
                            a = bp[jj];
                            #pragma unroll
                            for (int c = 0; c < 7; ++c) a = fmaf(Wp[jj * 9 + c], xcR[c], a);
                            a = fmaf(Wp[jj * 9 + 7], cpR, a);
                            a = fmaf(Wp[jj * 9 + 8], spR, a);
                        }
                        fd[e] = a;
                    }
                    #pragma unroll
                    for (int cc = 0; cc < 8; ++cc) {
                        const float4 cv = ((const float4*)(cb + (size_t)(lane * 8 + cc) * CDIM))[d4];
                        a0[cc] = fmaf(fd[0], cv.x, a0[cc]);
                        a1[cc] = fmaf(fd[1], cv.y, a1[cc]);
                        a2[cc] = fmaf(fd[2], cv.z, a2[cc]);
                        a3[cc] = fmaf(fd[3], cv.w, a3[cc]);
                    }
                }
                unsigned long long pbest = ~0ull;
                #pragma unroll
                for (int cc = 0; cc < 8; ++cc) {
                    const int kk = lane * 8 + cc;
                    float sc = fmaf(-2.0f, (a0[cc] + a1[cc]) + (a2[cc] + a3[cc]), cn[kk]);
                    unsigned long long pk = packsi(sc, kk);
                    pbest = pk < pbest ? pk : pbest;
                }
                #pragma unroll
                for (int m = 1; m <= 32; m <<= 1) {
                    unsigned long long o = __shfl_xor(pbest, m, 64);
                    pbest = o < pbest ? o : pbest;
                }
                if (lane == 0) {
                    const int bi = (int)(pbest & 0xFFFFFFFFu);
                    s_idx[row] = bi;
                    out_i[p0 + row] = (float)bi;
                }
            }
        }
    __syncthreads();

    // ---- cooperative coalesced gather of quantized rows (L2-hot cb) ----
    float4* oq = (float4*)out_q;
    const float4* c4g = (const float4*)cb;
    for (int i = tid; i < PTS * 16; i += 256) {
        const int pt = i >> 4;
        const int q = i & 15;
        oq[(size_t)(p0 + pt) * 16 + q] = c4g[(size_t)s_idx[pt] * 16 + q];
    }
}

extern "C" void kernel_launch(void* const* d_in, const int* in_sizes, int n_in,
                              void* d_out, int out_size, void* d_ws, size_t ws_size,
                              hipStream_t stream) {
    const float* imu = (const float*)d_in[0];
    const float* Wm  = (const float*)d_in[1];
    const float* bm  = (const float*)d_in[2];
    const float* Wp  = (const float*)d_in[3];
    const float* bp  = (const float*)d_in[4];
    const float* cb  = (const float*)d_in[5];

    float* out_q = (float*)d_out;                          // (32,4096,64)
    float* out_i = out_q + (size_t)NB * TN * CDIM;         // (32,4096) as float
    float* out_p = out_i + (size_t)NB * TN;                // (32,4096) phases

    float* cn     = (float*)d_ws;                          // 512 f32
    f16x8* cbswz  = (f16x8*)((char*)d_ws + 2048);          // 128 KB pre-swizzled
    f16x8* atiles = (f16x8*)out_q;                         // A-tiles staged in out_q

    prep_kernel<<<545, 256, 0, stream>>>(cb, cn, cbswz, out_p);
    hilbert_phase_kernel<<<NB * NCH / 2, HT, 0, stream>>>(imu, out_p);
    feat_kernel<<<(NB * TN) / 256, 256, 0, stream>>>(imu, Wm, bm, Wp, bp, out_p, atiles);
    vq_kernel<<<(NB * TN) / PTS, 256, 0, stream>>>(imu, Wm, bm, Wp, bp, cb,
                                                   cn, cbswz, out_p, atiles,
                                                   out_q, out_i);
}